// Round 2
// baseline (8530.719 us; speedup 1.0000x reference)
//
#include <hip/hip_runtime.h>
#include <stdint.h>

typedef _Float16 f16x8 __attribute__((ext_vector_type(8)));
typedef float    f32x4 __attribute__((ext_vector_type(4)));

#define D 128

// ---------------- utility ----------------
__global__ void k_zero4(uint4* __restrict__ p, int n4) {
  int t = blockIdx.x * blockDim.x + threadIdx.x;
  if (t < n4) p[t] = make_uint4(0u, 0u, 0u, 0u);
}

// Detect whether edge_index is int64 (odd u32 words all zero) or int32.
// flag[0] = 1 -> int64 layout (index stride 2 in u32 words), 0 -> int32.
__global__ void k_detect(const uint32_t* __restrict__ e, uint32_t* __restrict__ flag) {
  __shared__ uint32_t red[64];
  uint32_t v = 0;
  for (int i = threadIdx.x; i < 1024; i += 64) v |= e[2 * i + 1];
  red[threadIdx.x] = v;
  __syncthreads();
  if (threadIdx.x == 0) {
    uint32_t a = 0;
#pragma unroll
    for (int i = 0; i < 64; ++i) a |= red[i];
    flag[0] = (a == 0u) ? 1u : 0u;
  }
}

__global__ void k_count(const uint32_t* __restrict__ edges, const uint32_t* __restrict__ flag,
                        uint32_t* __restrict__ deg, int E) {
  int e = blockIdx.x * blockDim.x + threadIdx.x;
  if (e >= E) return;
  uint32_t f = flag[0];
  int d = (int)edges[((size_t)(E + e)) << f];
  atomicAdd(&deg[d], 1u);
}

__global__ void k_dinv(const uint32_t* __restrict__ deg, float* __restrict__ dinv, int N) {
  int n = blockIdx.x * blockDim.x + threadIdx.x;
  if (n < N) dinv[n] = rsqrtf((float)deg[n] + 1.0f);
}

// ---------------- GEMM: out16[N,128] = A[N,128] @ W[128,128] ----------------
// A is f32 (AF32=1) or f16 (AF32=0); W is f32; converts to f16 in staging; MFMA f16, f32 acc.
template <int AF32>
__global__ __launch_bounds__(256) void k_gemm(const void* __restrict__ Av,
                                              const float* __restrict__ W,
                                              _Float16* __restrict__ out, int N)
{
  __shared__ alignas(16) _Float16 xs[64][136];   // +8 pad: 2-way bank alias max (free)
  __shared__ alignas(16) _Float16 wt[128][136];  // wt[n][k] = W[k][n]

  const int tid  = threadIdx.x;
  const int row0 = blockIdx.x * 64;

  // stage 64 rows of A (row-clamped; output writes are guarded)
  for (int i = tid; i < 64 * 16; i += 256) {
    int r = i >> 4, c = (i & 15) * 8;
    int gr = row0 + r; if (gr >= N) gr = N - 1;
    f16x8 v;
    if (AF32) {
      const f32x4* p = reinterpret_cast<const f32x4*>((const float*)Av + (size_t)gr * D + c);
      f32x4 a = p[0], b = p[1];
#pragma unroll
      for (int j = 0; j < 4; ++j) { v[j] = (_Float16)a[j]; v[j + 4] = (_Float16)b[j]; }
    } else {
      v = *reinterpret_cast<const f16x8*>((const _Float16*)Av + (size_t)gr * D + c);
    }
    *reinterpret_cast<f16x8*>(&xs[r][c]) = v;
  }
  // stage W transposed (f32 -> f16)
  for (int i = tid; i < 128 * 16; i += 256) {
    int k = i >> 4, n0 = (i & 15) * 8;
    const f32x4* p = reinterpret_cast<const f32x4*>(W + k * D + n0);
    f32x4 a = p[0], b = p[1];
#pragma unroll
    for (int j = 0; j < 4; ++j) { wt[n0 + j][k] = (_Float16)a[j]; wt[n0 + 4 + j][k] = (_Float16)b[j]; }
  }
  __syncthreads();

  const int wave = tid >> 6, lane = tid & 63;
  const int m16 = lane & 15, khi = lane >> 4;   // khi in 0..3
  const int wrow = wave * 16;

  f32x4 acc[8] = {};
#pragma unroll
  for (int kk = 0; kk < 4; ++kk) {
    f16x8 a = *reinterpret_cast<const f16x8*>(&xs[wrow + m16][kk * 32 + khi * 8]);
#pragma unroll
    for (int c = 0; c < 8; ++c) {
      f16x8 b = *reinterpret_cast<const f16x8*>(&wt[c * 16 + m16][kk * 32 + khi * 8]);
      acc[c] = __builtin_amdgcn_mfma_f32_16x16x32_f16(a, b, acc[c], 0, 0, 0);
    }
  }

  // C/D layout: col = lane&15, row = khi*4 + j  (dtype-independent, m89/m121)
#pragma unroll
  for (int c = 0; c < 8; ++c) {
#pragma unroll
    for (int j = 0; j < 4; ++j) {
      int gr = row0 + wrow + khi * 4 + j;
      if (gr < N) out[(size_t)gr * D + c * 16 + m16] = (_Float16)acc[c][j];
    }
  }
}

// ---------------- edge scatter: S[dst] += H[src] * dinv[src]*dinv[dst] ----------------
__global__ void k_scatter(const _Float16* __restrict__ H, const uint32_t* __restrict__ edges,
                          const uint32_t* __restrict__ flag, const float* __restrict__ dinv,
                          float* __restrict__ S, int E)
{
  int t = blockIdx.x * blockDim.x + threadIdx.x;
  int e = t >> 4;
  if (e >= E) return;
  uint32_t f = flag[0];
  int s = (int)edges[(size_t)e << f];
  int d = (int)edges[((size_t)(E + e)) << f];
  int c0 = (t & 15) * 8;
  float nrm = dinv[s] * dinv[d];
  f16x8 h = *reinterpret_cast<const f16x8*>(H + (size_t)s * D + c0);
  float* o = S + (size_t)d * D + c0;
#pragma unroll
  for (int j = 0; j < 8; ++j) atomicAdd(o + j, (float)h[j] * nrm);
}

// ---------------- finalize: out = S + G*dinv^2 + bias (opt ReLU); f16 or f32 out ----------
template <int RELU, int OUTF16>
__global__ void k_finalize(const float* __restrict__ S, const _Float16* __restrict__ G,
                           const float* __restrict__ dinv, const float* __restrict__ bias,
                           void* __restrict__ outv, int N)
{
  int t = blockIdx.x * blockDim.x + threadIdx.x;
  if (t >= N * 16) return;
  int n = t >> 4, c0 = (t & 15) * 8;
  float di = dinv[n], di2 = di * di;
  const f32x4* sp = reinterpret_cast<const f32x4*>(S + (size_t)n * D + c0);
  f32x4 s0 = sp[0], s1 = sp[1];
  f16x8 g = *reinterpret_cast<const f16x8*>(G + (size_t)n * D + c0);
  const f32x4* bp = reinterpret_cast<const f32x4*>(bias + c0);
  f32x4 b0 = bp[0], b1 = bp[1];
  float v[8];
#pragma unroll
  for (int j = 0; j < 8; ++j) {
    float sv = (j < 4) ? s0[j] : s1[j - 4];
    float bv = (j < 4) ? b0[j] : b1[j - 4];
    float r = sv + (float)g[j] * di2 + bv;
    if (RELU) r = r > 0.f ? r : 0.f;
    v[j] = r;
  }
  if (OUTF16) {
    f16x8 o;
#pragma unroll
    for (int j = 0; j < 8; ++j) o[j] = (_Float16)v[j];
    *reinterpret_cast<f16x8*>((_Float16*)outv + (size_t)n * D + c0) = o;
  } else {
    f32x4 o0, o1;
#pragma unroll
    for (int j = 0; j < 4; ++j) { o0[j] = v[j]; o1[j] = v[j + 4]; }
    f32x4* op = reinterpret_cast<f32x4*>((float*)outv + (size_t)n * D + c0);
    op[0] = o0; op[1] = o1;
  }
}

// ---------------- launcher ----------------
extern "C" void kernel_launch(void* const* d_in, const int* in_sizes, int n_in,
                              void* d_out, int out_size, void* d_ws, size_t ws_size,
                              hipStream_t stream) {
  const int N = in_sizes[0] / D;   // 50000
  const int E = in_sizes[1] / 2;   // 800000

  const float* x        = (const float*)d_in[0];
  const uint32_t* edges = (const uint32_t*)d_in[1];
  const float* W1  = (const float*)d_in[2];
  const float* b1  = (const float*)d_in[3];
  const float* Wmu = (const float*)d_in[4];
  const float* bmu = (const float*)d_in[5];
  const float* Wls = (const float*)d_in[6];
  const float* bls = (const float*)d_in[7];
  float* out_mu = (float*)d_out;
  float* out_ls = out_mu + (size_t)N * D;

  // workspace carve (1MB-aligned regions)
  char* w = (char*)d_ws;
  uint32_t* deg  = (uint32_t*)(w);                    // N u32
  float*    dinv = (float*)(w + 262144);              // N f32
  uint32_t* flag = (uint32_t*)(w + 524288);           // 1 u32
  _Float16* G16  = (_Float16*)(w + (1u << 20));       // N*D f16 (GEMM out)
  _Float16* h16  = (_Float16*)(w + (14u << 20));      // N*D f16 (relu'd layer-1)
  float*    S    = (float*)(w + (27u << 20));         // N*D f32 (edge agg)
  size_t need = (27u << 20) + (size_t)N * D * 4;
  if (ws_size < need) return;  // -> zeros out, fails loudly with absmax = max|ref|

  const int nS4   = N * D / 4;
  const int nDeg4 = (N + 3) / 4;

  k_detect<<<1, 64, 0, stream>>>(edges, flag);
  k_zero4<<<(nDeg4 + 255) / 256, 256, 0, stream>>>((uint4*)deg, nDeg4);
  k_count<<<(E + 255) / 256, 256, 0, stream>>>(edges, flag, deg, E);
  k_dinv<<<(N + 255) / 256, 256, 0, stream>>>(deg, dinv, N);

  const int gemmGrid = (N + 63) / 64;
  const int scatGrid = (E * 16 + 255) / 256;
  const int finGrid  = (N * 16 + 255) / 256;
  const int zeroGrid = (nS4 + 255) / 256;

  // conv1: h = relu(agg(x@W1) + b1)
  k_gemm<1><<<gemmGrid, 256, 0, stream>>>((const void*)x, W1, G16, N);
  k_zero4<<<zeroGrid, 256, 0, stream>>>((uint4*)S, nS4);
  k_scatter<<<scatGrid, 256, 0, stream>>>(G16, edges, flag, dinv, S, E);
  k_finalize<1, 1><<<finGrid, 256, 0, stream>>>(S, G16, dinv, b1, (void*)h16, N);

  // conv_mu: out_mu = agg(h@Wmu) + bmu
  k_gemm<0><<<gemmGrid, 256, 0, stream>>>((const void*)h16, Wmu, G16, N);
  k_zero4<<<zeroGrid, 256, 0, stream>>>((uint4*)S, nS4);
  k_scatter<<<scatGrid, 256, 0, stream>>>(G16, edges, flag, dinv, S, E);
  k_finalize<0, 0><<<finGrid, 256, 0, stream>>>(S, G16, dinv, bmu, (void*)out_mu, N);

  // conv_ls: out_ls = agg(h@Wls) + bls
  k_gemm<0><<<gemmGrid, 256, 0, stream>>>((const void*)h16, Wls, G16, N);
  k_zero4<<<zeroGrid, 256, 0, stream>>>((uint4*)S, nS4);
  k_scatter<<<scatGrid, 256, 0, stream>>>(G16, edges, flag, dinv, S, E);
  k_finalize<0, 0><<<finGrid, 256, 0, stream>>>(S, G16, dinv, bls, (void*)out_ls, N);
}

// Round 3
// 362.118 us; speedup vs baseline: 23.5579x; 23.5579x over previous
//
#include <hip/hip_runtime.h>
#include <stdint.h>

typedef _Float16 f16x8 __attribute__((ext_vector_type(8)));
typedef float    f32x4 __attribute__((ext_vector_type(4)));

#define D 128

// ---------------- utility ----------------
__global__ void k_zero4(uint4* __restrict__ p, int n4) {
  int t = blockIdx.x * blockDim.x + threadIdx.x;
  if (t < n4) p[t] = make_uint4(0u, 0u, 0u, 0u);
}

// Detect whether edge_index is int64 (odd u32 words all zero) or int32.
__global__ void k_detect(const uint32_t* __restrict__ e, uint32_t* __restrict__ flag) {
  __shared__ uint32_t red[64];
  uint32_t v = 0;
  for (int i = threadIdx.x; i < 1024; i += 64) v |= e[2 * i + 1];
  red[threadIdx.x] = v;
  __syncthreads();
  if (threadIdx.x == 0) {
    uint32_t a = 0;
#pragma unroll
    for (int i = 0; i < 64; ++i) a |= red[i];
    flag[0] = (a == 0u) ? 1u : 0u;
  }
}

__global__ void k_count(const uint32_t* __restrict__ edges, const uint32_t* __restrict__ flag,
                        uint32_t* __restrict__ deg, int E) {
  int e = blockIdx.x * blockDim.x + threadIdx.x;
  if (e >= E) return;
  uint32_t f = flag[0];
  int d = (int)edges[((size_t)(E + e)) << f];
  atomicAdd(&deg[d], 1u);
}

__global__ void k_dinv(const uint32_t* __restrict__ deg, float* __restrict__ dinv, int N) {
  int n = blockIdx.x * blockDim.x + threadIdx.x;
  if (n < N) dinv[n] = rsqrtf((float)deg[n] + 1.0f);
}

// Exclusive prefix sum of deg -> rowptr[0..N], cursor copy. Single block, 1024 threads.
__global__ __launch_bounds__(1024) void k_scan(const uint32_t* __restrict__ deg,
                                               uint32_t* __restrict__ rowptr,
                                               uint32_t* __restrict__ cursor, int N) {
  __shared__ uint32_t buf[1024];
  __shared__ uint32_t carry;
  if (threadIdx.x == 0) carry = 0u;
  __syncthreads();
  for (int base = 0; base < N; base += 1024) {
    int i = base + threadIdx.x;
    uint32_t v = (i < N) ? deg[i] : 0u;
    buf[threadIdx.x] = v;
    __syncthreads();
#pragma unroll
    for (int off = 1; off < 1024; off <<= 1) {
      uint32_t t = (threadIdx.x >= (unsigned)off) ? buf[threadIdx.x - off] : 0u;
      __syncthreads();
      buf[threadIdx.x] += t;
      __syncthreads();
    }
    uint32_t excl = carry + buf[threadIdx.x] - v;
    if (i < N) {
      rowptr[i] = excl;
      cursor[i] = excl;
      if (i == N - 1) rowptr[N] = excl + v;
    }
    __syncthreads();
    if (threadIdx.x == 0) carry += buf[1023];
    __syncthreads();
  }
}

// Bucket edges by dst: csr_src[pos]=src, csr_nrm[pos]=dinv[src]*dinv[dst]
__global__ void k_fill(const uint32_t* __restrict__ edges, const uint32_t* __restrict__ flag,
                       const float* __restrict__ dinv, uint32_t* __restrict__ cursor,
                       uint32_t* __restrict__ csr_src, float* __restrict__ csr_nrm, int E) {
  int e = blockIdx.x * blockDim.x + threadIdx.x;
  if (e >= E) return;
  uint32_t f = flag[0];
  int s = (int)edges[(size_t)e << f];
  int d = (int)edges[((size_t)(E + e)) << f];
  uint32_t pos = atomicAdd(&cursor[d], 1u);
  csr_src[pos] = (uint32_t)s;
  csr_nrm[pos] = dinv[s] * dinv[d];
}

// ---------------- GEMM: out16[N,128] = A[N,128] @ W[128,128] ----------------
template <int AF32>
__global__ __launch_bounds__(256) void k_gemm(const void* __restrict__ Av,
                                              const float* __restrict__ W,
                                              _Float16* __restrict__ out, int N)
{
  __shared__ alignas(16) _Float16 xs[64][136];
  __shared__ alignas(16) _Float16 wt[128][136];  // wt[n][k] = W[k][n]

  const int tid  = threadIdx.x;
  const int row0 = blockIdx.x * 64;

  for (int i = tid; i < 64 * 16; i += 256) {
    int r = i >> 4, c = (i & 15) * 8;
    int gr = row0 + r; if (gr >= N) gr = N - 1;
    f16x8 v;
    if (AF32) {
      const f32x4* p = reinterpret_cast<const f32x4*>((const float*)Av + (size_t)gr * D + c);
      f32x4 a = p[0], b = p[1];
#pragma unroll
      for (int j = 0; j < 4; ++j) { v[j] = (_Float16)a[j]; v[j + 4] = (_Float16)b[j]; }
    } else {
      v = *reinterpret_cast<const f16x8*>((const _Float16*)Av + (size_t)gr * D + c);
    }
    *reinterpret_cast<f16x8*>(&xs[r][c]) = v;
  }
  for (int i = tid; i < 128 * 16; i += 256) {
    int k = i >> 4, n0 = (i & 15) * 8;
    const f32x4* p = reinterpret_cast<const f32x4*>(W + k * D + n0);
    f32x4 a = p[0], b = p[1];
#pragma unroll
    for (int j = 0; j < 4; ++j) { wt[n0 + j][k] = (_Float16)a[j]; wt[n0 + 4 + j][k] = (_Float16)b[j]; }
  }
  __syncthreads();

  const int wave = tid >> 6, lane = tid & 63;
  const int m16 = lane & 15, khi = lane >> 4;
  const int wrow = wave * 16;

  f32x4 acc[8] = {};
#pragma unroll
  for (int kk = 0; kk < 4; ++kk) {
    f16x8 a = *reinterpret_cast<const f16x8*>(&xs[wrow + m16][kk * 32 + khi * 8]);
#pragma unroll
    for (int c = 0; c < 8; ++c) {
      f16x8 b = *reinterpret_cast<const f16x8*>(&wt[c * 16 + m16][kk * 32 + khi * 8]);
      acc[c] = __builtin_amdgcn_mfma_f32_16x16x32_f16(a, b, acc[c], 0, 0, 0);
    }
  }

#pragma unroll
  for (int c = 0; c < 8; ++c) {
#pragma unroll
    for (int j = 0; j < 4; ++j) {
      int gr = row0 + wrow + khi * 4 + j;
      if (gr < N) out[(size_t)gr * D + c * 16 + m16] = (_Float16)acc[c][j];
    }
  }
}

// ---------------- gather-aggregate + fused finalize ----------------
// out = sum_{e: dst=n} G[src_e]*nrm_e + G[n]*dinv[n]^2 + bias  (opt ReLU)
// 16 threads per node, 8 cols each. DUAL processes two feature matrices per index read.
template <int RELU, int OUTF16, int DUAL>
__global__ __launch_bounds__(256) void k_agg(
    const _Float16* __restrict__ Ga, const _Float16* __restrict__ Gb,
    const uint32_t* __restrict__ rowptr, const uint32_t* __restrict__ csr_src,
    const float* __restrict__ csr_nrm, const float* __restrict__ dinv,
    const float* __restrict__ ba, const float* __restrict__ bb,
    void* __restrict__ oa, void* __restrict__ ob, int N)
{
  int t = blockIdx.x * blockDim.x + threadIdx.x;
  int n = t >> 4;
  if (n >= N) return;
  int c0 = (t & 15) * 8;

  uint32_t j0 = rowptr[n], j1 = rowptr[n + 1];
  float acca[8] = {};
  float accb[8] = {};
  for (uint32_t j = j0; j < j1; ++j) {
    uint32_t s = csr_src[j];
    float wv = csr_nrm[j];
    f16x8 ha = *reinterpret_cast<const f16x8*>(Ga + (size_t)s * D + c0);
#pragma unroll
    for (int q = 0; q < 8; ++q) acca[q] += (float)ha[q] * wv;
    if (DUAL) {
      f16x8 hb = *reinterpret_cast<const f16x8*>(Gb + (size_t)s * D + c0);
#pragma unroll
      for (int q = 0; q < 8; ++q) accb[q] += (float)hb[q] * wv;
    }
  }

  float di = dinv[n], di2 = di * di;
  f16x8 ga = *reinterpret_cast<const f16x8*>(Ga + (size_t)n * D + c0);
  const f32x4* bpa = reinterpret_cast<const f32x4*>(ba + c0);
  f32x4 ba0 = bpa[0], ba1 = bpa[1];
  float va[8];
#pragma unroll
  for (int q = 0; q < 8; ++q) {
    float bv = (q < 4) ? ba0[q] : ba1[q - 4];
    float r = acca[q] + (float)ga[q] * di2 + bv;
    if (RELU) r = r > 0.f ? r : 0.f;
    va[q] = r;
  }
  if (OUTF16) {
    f16x8 o;
#pragma unroll
    for (int q = 0; q < 8; ++q) o[q] = (_Float16)va[q];
    *reinterpret_cast<f16x8*>((_Float16*)oa + (size_t)n * D + c0) = o;
  } else {
    f32x4 o0, o1;
#pragma unroll
    for (int q = 0; q < 4; ++q) { o0[q] = va[q]; o1[q] = va[q + 4]; }
    f32x4* op = reinterpret_cast<f32x4*>((float*)oa + (size_t)n * D + c0);
    op[0] = o0; op[1] = o1;
  }

  if (DUAL) {
    f16x8 gb = *reinterpret_cast<const f16x8*>(Gb + (size_t)n * D + c0);
    const f32x4* bpb = reinterpret_cast<const f32x4*>(bb + c0);
    f32x4 bb0 = bpb[0], bb1 = bpb[1];
    float vb[8];
#pragma unroll
    for (int q = 0; q < 8; ++q) {
      float bv = (q < 4) ? bb0[q] : bb1[q - 4];
      vb[q] = accb[q] + (float)gb[q] * di2 + bv;
    }
    f32x4 o0, o1;
#pragma unroll
    for (int q = 0; q < 4; ++q) { o0[q] = vb[q]; o1[q] = vb[q + 4]; }
    f32x4* op = reinterpret_cast<f32x4*>((float*)ob + (size_t)n * D + c0);
    op[0] = o0; op[1] = o1;
  }
}

// ---------------- launcher ----------------
extern "C" void kernel_launch(void* const* d_in, const int* in_sizes, int n_in,
                              void* d_out, int out_size, void* d_ws, size_t ws_size,
                              hipStream_t stream) {
  const int N = in_sizes[0] / D;   // 50000
  const int E = in_sizes[1] / 2;   // 800000

  const float* x        = (const float*)d_in[0];
  const uint32_t* edges = (const uint32_t*)d_in[1];
  const float* W1  = (const float*)d_in[2];
  const float* b1  = (const float*)d_in[3];
  const float* Wmu = (const float*)d_in[4];
  const float* bmu = (const float*)d_in[5];
  const float* Wls = (const float*)d_in[6];
  const float* bls = (const float*)d_in[7];
  float* out_mu = (float*)d_out;
  float* out_ls = out_mu + (size_t)N * D;

  // workspace carve
  char* w = (char*)d_ws;
  uint32_t* deg    = (uint32_t*)(w);                  // N u32
  float*    dinv   = (float*)(w + (256u << 10));      // N f32
  uint32_t* flag   = (uint32_t*)(w + (512u << 10));   // 1 u32
  uint32_t* rowptr = (uint32_t*)(w + (768u << 10));   // N+1 u32
  uint32_t* cursor = (uint32_t*)(w + (1u << 20));     // N u32
  uint32_t* csr_src= (uint32_t*)(w + (2u << 20));     // E u32 (3.2MB)
  float*    csr_nrm= (float*)(w + (6u << 20));        // E f32 (3.2MB)
  _Float16* G16    = (_Float16*)(w + (10u << 20));    // N*D f16 (conv1 G; reused as Gmu)
  _Float16* h16    = (_Float16*)(w + (23u << 20));    // N*D f16
  _Float16* Gls16  = (_Float16*)(w + (36u << 20));    // N*D f16
  size_t need = (36u << 20) + (size_t)N * D * 2;
  if (ws_size < need) return;

  const int nDeg4 = (N + 3) / 4;

  k_detect<<<1, 64, 0, stream>>>(edges, flag);
  k_zero4<<<(nDeg4 + 255) / 256, 256, 0, stream>>>((uint4*)deg, nDeg4);
  k_count<<<(E + 255) / 256, 256, 0, stream>>>(edges, flag, deg, E);
  k_dinv<<<(N + 255) / 256, 256, 0, stream>>>(deg, dinv, N);
  k_scan<<<1, 1024, 0, stream>>>(deg, rowptr, cursor, N);
  k_fill<<<(E + 255) / 256, 256, 0, stream>>>(edges, flag, dinv, cursor, csr_src, csr_nrm, E);

  const int gemmGrid = (N + 63) / 64;
  const int aggGrid  = (N * 16 + 255) / 256;

  // conv1: h = relu(agg(x@W1) + b1)
  k_gemm<1><<<gemmGrid, 256, 0, stream>>>((const void*)x, W1, G16, N);
  k_agg<1, 1, 0><<<aggGrid, 256, 0, stream>>>(G16, (const _Float16*)nullptr, rowptr, csr_src,
                                              csr_nrm, dinv, b1, (const float*)nullptr,
                                              (void*)h16, (void*)nullptr, N);

  // mu & logstd GEMMs (Gmu reuses G16 buffer)
  k_gemm<0><<<gemmGrid, 256, 0, stream>>>((const void*)h16, Wmu, G16, N);
  k_gemm<0><<<gemmGrid, 256, 0, stream>>>((const void*)h16, Wls, Gls16, N);

  // fused dual aggregation -> out_mu, out_ls (f32)
  k_agg<0, 0, 1><<<aggGrid, 256, 0, stream>>>(G16, Gls16, rowptr, csr_src, csr_nrm, dinv,
                                              bmu, bls, (void*)out_mu, (void*)out_ls, N);
}

// Round 4
// 270.031 us; speedup vs baseline: 31.5916x; 1.3410x over previous
//
#include <hip/hip_runtime.h>
#include <stdint.h>

typedef _Float16 f16x8 __attribute__((ext_vector_type(8)));
typedef float    f32x4 __attribute__((ext_vector_type(4)));

#define D 128

// ---------------- utility ----------------
__global__ void k_zero4(uint4* __restrict__ p, int n4) {
  int t = blockIdx.x * blockDim.x + threadIdx.x;
  if (t < n4) p[t] = make_uint4(0u, 0u, 0u, 0u);
}

// Detect whether edge_index is int64 (odd u32 words all zero) or int32.
__global__ void k_detect(const uint32_t* __restrict__ e, uint32_t* __restrict__ flag) {
  __shared__ uint32_t red[64];
  uint32_t v = 0;
  for (int i = threadIdx.x; i < 1024; i += 64) v |= e[2 * i + 1];
  red[threadIdx.x] = v;
  __syncthreads();
  if (threadIdx.x == 0) {
    uint32_t a = 0;
#pragma unroll
    for (int i = 0; i < 64; ++i) a |= red[i];
    flag[0] = (a == 0u) ? 1u : 0u;
  }
}

__global__ void k_count(const uint32_t* __restrict__ edges, const uint32_t* __restrict__ flag,
                        uint32_t* __restrict__ deg, int E) {
  int e = blockIdx.x * blockDim.x + threadIdx.x;
  if (e >= E) return;
  uint32_t f = flag[0];
  int d = (int)edges[((size_t)(E + e)) << f];
  atomicAdd(&deg[d], 1u);
}

// ---------------- multi-block exclusive scan of deg -> rowptr/cursor ----------------
// 1024 elements per block. nb = ceil(N/1024) (49 for N=50000).
__global__ __launch_bounds__(256) void k_scan1(const uint32_t* __restrict__ deg,
                                               uint32_t* __restrict__ bsum, int N) {
  int i0 = blockIdx.x * 1024 + threadIdx.x * 4;
  uint32_t s = 0;
  if (i0 + 3 < N) {
    uint4 v = *reinterpret_cast<const uint4*>(deg + i0);
    s = v.x + v.y + v.z + v.w;
  } else {
    for (int j = 0; j < 4; ++j) if (i0 + j < N) s += deg[i0 + j];
  }
#pragma unroll
  for (int off = 1; off < 64; off <<= 1) s += __shfl_xor(s, off);
  __shared__ uint32_t ws[4];
  if ((threadIdx.x & 63) == 0) ws[threadIdx.x >> 6] = s;
  __syncthreads();
  if (threadIdx.x == 0) bsum[blockIdx.x] = ws[0] + ws[1] + ws[2] + ws[3];
}

// In-place exclusive scan of bsum[0..nb), single wave, serial 64-chunks with carry.
__global__ void k_scan2(uint32_t* __restrict__ bsum, int nb) {
  int t = threadIdx.x;  // 64 threads
  uint32_t carry = 0;
  for (int base = 0; base < nb; base += 64) {
    uint32_t v = (base + t < nb) ? bsum[base + t] : 0u;
    uint32_t inc = v;
#pragma unroll
    for (int off = 1; off < 64; off <<= 1) {
      uint32_t u = __shfl_up(inc, off);
      if (t >= off) inc += u;
    }
    uint32_t ex = __shfl_up(inc, 1);
    if (t == 0) ex = 0u;
    if (base + t < nb) bsum[base + t] = carry + ex;
    carry += __shfl(inc, 63);
  }
}

__global__ __launch_bounds__(256) void k_scan3(const uint32_t* __restrict__ deg,
                                               const uint32_t* __restrict__ bsum,
                                               uint32_t* __restrict__ rowptr,
                                               uint32_t* __restrict__ cursor, int N, int E) {
  int i0 = blockIdx.x * 1024 + threadIdx.x * 4;
  uint32_t v[4];
  uint32_t s = 0;
#pragma unroll
  for (int j = 0; j < 4; ++j) { v[j] = (i0 + j < N) ? deg[i0 + j] : 0u; s += v[j]; }
  int lane = threadIdx.x & 63, wid = threadIdx.x >> 6;
  uint32_t inc = s;
#pragma unroll
  for (int off = 1; off < 64; off <<= 1) {
    uint32_t u = __shfl_up(inc, off);
    if (lane >= off) inc += u;
  }
  __shared__ uint32_t wsum[4];
  if (lane == 63) wsum[wid] = inc;
  __syncthreads();
  uint32_t woff = 0;
#pragma unroll
  for (int k = 0; k < 4; ++k) if (k < wid) woff += wsum[k];
  uint32_t run = bsum[blockIdx.x] + woff + (inc - s);
#pragma unroll
  for (int j = 0; j < 4; ++j) {
    int i = i0 + j;
    if (i < N) { rowptr[i] = run; cursor[i] = run; }
    run += v[j];
  }
  if (blockIdx.x == 0 && threadIdx.x == 0) rowptr[N] = (uint32_t)E;
}

// Bucket edges by dst: csr_src[pos]=src, csr_nrm[pos]=rsqrt((deg_s+1)(deg_d+1))
__global__ void k_fill(const uint32_t* __restrict__ edges, const uint32_t* __restrict__ flag,
                       const uint32_t* __restrict__ deg, uint32_t* __restrict__ cursor,
                       uint32_t* __restrict__ csr_src, float* __restrict__ csr_nrm, int E) {
  int e = blockIdx.x * blockDim.x + threadIdx.x;
  if (e >= E) return;
  uint32_t f = flag[0];
  int s = (int)edges[(size_t)e << f];
  int d = (int)edges[((size_t)(E + e)) << f];
  uint32_t pos = atomicAdd(&cursor[d], 1u);
  csr_src[pos] = (uint32_t)s;
  csr_nrm[pos] = rsqrtf((float)(deg[s] + 1u) * (float)(deg[d] + 1u));
}

// ---------------- GEMM: out16[N,128] = A[N,128] @ W[128,128] ----------------
template <int AF32>
__global__ __launch_bounds__(256) void k_gemm(const void* __restrict__ Av,
                                              const float* __restrict__ W,
                                              _Float16* __restrict__ out, int N)
{
  __shared__ alignas(16) _Float16 xs[64][136];
  __shared__ alignas(16) _Float16 wt[128][136];  // wt[n][k] = W[k][n]

  const int tid  = threadIdx.x;
  const int row0 = blockIdx.x * 64;

  for (int i = tid; i < 64 * 16; i += 256) {
    int r = i >> 4, c = (i & 15) * 8;
    int gr = row0 + r; if (gr >= N) gr = N - 1;
    f16x8 v;
    if (AF32) {
      const f32x4* p = reinterpret_cast<const f32x4*>((const float*)Av + (size_t)gr * D + c);
      f32x4 a = p[0], b = p[1];
#pragma unroll
      for (int j = 0; j < 4; ++j) { v[j] = (_Float16)a[j]; v[j + 4] = (_Float16)b[j]; }
    } else {
      v = *reinterpret_cast<const f16x8*>((const _Float16*)Av + (size_t)gr * D + c);
    }
    *reinterpret_cast<f16x8*>(&xs[r][c]) = v;
  }
  for (int i = tid; i < 128 * 16; i += 256) {
    int k = i >> 4, n0 = (i & 15) * 8;
    const f32x4* p = reinterpret_cast<const f32x4*>(W + k * D + n0);
    f32x4 a = p[0], b = p[1];
#pragma unroll
    for (int j = 0; j < 4; ++j) { wt[n0 + j][k] = (_Float16)a[j]; wt[n0 + 4 + j][k] = (_Float16)b[j]; }
  }
  __syncthreads();

  const int wave = tid >> 6, lane = tid & 63;
  const int m16 = lane & 15, khi = lane >> 4;
  const int wrow = wave * 16;

  f32x4 acc[8] = {};
#pragma unroll
  for (int kk = 0; kk < 4; ++kk) {
    f16x8 a = *reinterpret_cast<const f16x8*>(&xs[wrow + m16][kk * 32 + khi * 8]);
#pragma unroll
    for (int c = 0; c < 8; ++c) {
      f16x8 b = *reinterpret_cast<const f16x8*>(&wt[c * 16 + m16][kk * 32 + khi * 8]);
      acc[c] = __builtin_amdgcn_mfma_f32_16x16x32_f16(a, b, acc[c], 0, 0, 0);
    }
  }

#pragma unroll
  for (int c = 0; c < 8; ++c) {
#pragma unroll
    for (int j = 0; j < 4; ++j) {
      int gr = row0 + wrow + khi * 4 + j;
      if (gr < N) out[(size_t)gr * D + c * 16 + m16] = (_Float16)acc[c][j];
    }
  }
}

// Fused dual GEMM: stage A once; Oa = A@Wa, Ob = A@Wb (A f16).
__global__ __launch_bounds__(256) void k_gemm2(const _Float16* __restrict__ A,
                                               const float* __restrict__ Wa,
                                               const float* __restrict__ Wb,
                                               _Float16* __restrict__ Oa,
                                               _Float16* __restrict__ Ob, int N)
{
  __shared__ alignas(16) _Float16 xs[64][136];
  __shared__ alignas(16) _Float16 wt[128][136];

  const int tid  = threadIdx.x;
  const int row0 = blockIdx.x * 64;

  for (int i = tid; i < 64 * 16; i += 256) {
    int r = i >> 4, c = (i & 15) * 8;
    int gr = row0 + r; if (gr >= N) gr = N - 1;
    *reinterpret_cast<f16x8*>(&xs[r][c]) =
        *reinterpret_cast<const f16x8*>(A + (size_t)gr * D + c);
  }

  const int wave = tid >> 6, lane = tid & 63;
  const int m16 = lane & 15, khi = lane >> 4;
  const int wrow = wave * 16;

#pragma unroll
  for (int m = 0; m < 2; ++m) {
    const float* W = m ? Wb : Wa;
    _Float16* out = m ? Ob : Oa;
    if (m) __syncthreads();  // previous compute's LDS reads done before overwrite
    for (int i = tid; i < 128 * 16; i += 256) {
      int k = i >> 4, n0 = (i & 15) * 8;
      const f32x4* p = reinterpret_cast<const f32x4*>(W + k * D + n0);
      f32x4 a = p[0], b = p[1];
#pragma unroll
      for (int j = 0; j < 4; ++j) { wt[n0 + j][k] = (_Float16)a[j]; wt[n0 + 4 + j][k] = (_Float16)b[j]; }
    }
    __syncthreads();

    f32x4 acc[8] = {};
#pragma unroll
    for (int kk = 0; kk < 4; ++kk) {
      f16x8 a = *reinterpret_cast<const f16x8*>(&xs[wrow + m16][kk * 32 + khi * 8]);
#pragma unroll
      for (int c = 0; c < 8; ++c) {
        f16x8 b = *reinterpret_cast<const f16x8*>(&wt[c * 16 + m16][kk * 32 + khi * 8]);
        acc[c] = __builtin_amdgcn_mfma_f32_16x16x32_f16(a, b, acc[c], 0, 0, 0);
      }
    }
#pragma unroll
    for (int c = 0; c < 8; ++c) {
#pragma unroll
      for (int j = 0; j < 4; ++j) {
        int gr = row0 + wrow + khi * 4 + j;
        if (gr < N) out[(size_t)gr * D + c * 16 + m16] = (_Float16)acc[c][j];
      }
    }
  }
}

// ---------------- gather-aggregate + fused finalize ----------------
// out = sum_{e: dst=n} G[src_e]*nrm_e + G[n]/(deg[n]+1) + bias  (opt ReLU)
// 16 threads per node, 8 cols each; 2-edge unrolled for MLP.
template <int RELU, int OUTF16, int DUAL>
__global__ __launch_bounds__(256) void k_agg(
    const _Float16* __restrict__ Ga, const _Float16* __restrict__ Gb,
    const uint32_t* __restrict__ rowptr, const uint32_t* __restrict__ csr_src,
    const float* __restrict__ csr_nrm, const uint32_t* __restrict__ deg,
    const float* __restrict__ ba, const float* __restrict__ bb,
    void* __restrict__ oa, void* __restrict__ ob, int N)
{
  int t = blockIdx.x * blockDim.x + threadIdx.x;
  int n = t >> 4;
  if (n >= N) return;
  int c0 = (t & 15) * 8;

  uint32_t j0 = rowptr[n], j1 = rowptr[n + 1];
  float acca[8] = {};
  float accb[8] = {};
  uint32_t j = j0;
  for (; j + 2 <= j1; j += 2) {
    uint32_t s0 = csr_src[j], s1 = csr_src[j + 1];
    float w0 = csr_nrm[j], w1 = csr_nrm[j + 1];
    f16x8 ha0 = *reinterpret_cast<const f16x8*>(Ga + (size_t)s0 * D + c0);
    f16x8 ha1 = *reinterpret_cast<const f16x8*>(Ga + (size_t)s1 * D + c0);
    if (DUAL) {
      f16x8 hb0 = *reinterpret_cast<const f16x8*>(Gb + (size_t)s0 * D + c0);
      f16x8 hb1 = *reinterpret_cast<const f16x8*>(Gb + (size_t)s1 * D + c0);
#pragma unroll
      for (int q = 0; q < 8; ++q) {
        acca[q] += (float)ha0[q] * w0 + (float)ha1[q] * w1;
        accb[q] += (float)hb0[q] * w0 + (float)hb1[q] * w1;
      }
    } else {
#pragma unroll
      for (int q = 0; q < 8; ++q) acca[q] += (float)ha0[q] * w0 + (float)ha1[q] * w1;
    }
  }
  if (j < j1) {
    uint32_t s0 = csr_src[j];
    float w0 = csr_nrm[j];
    f16x8 ha0 = *reinterpret_cast<const f16x8*>(Ga + (size_t)s0 * D + c0);
#pragma unroll
    for (int q = 0; q < 8; ++q) acca[q] += (float)ha0[q] * w0;
    if (DUAL) {
      f16x8 hb0 = *reinterpret_cast<const f16x8*>(Gb + (size_t)s0 * D + c0);
#pragma unroll
      for (int q = 0; q < 8; ++q) accb[q] += (float)hb0[q] * w0;
    }
  }

  float di2 = 1.0f / (float)(deg[n] + 1u);
  f16x8 ga = *reinterpret_cast<const f16x8*>(Ga + (size_t)n * D + c0);
  const f32x4* bpa = reinterpret_cast<const f32x4*>(ba + c0);
  f32x4 ba0 = bpa[0], ba1 = bpa[1];
  float va[8];
#pragma unroll
  for (int q = 0; q < 8; ++q) {
    float bv = (q < 4) ? ba0[q] : ba1[q - 4];
    float r = acca[q] + (float)ga[q] * di2 + bv;
    if (RELU) r = r > 0.f ? r : 0.f;
    va[q] = r;
  }
  if (OUTF16) {
    f16x8 o;
#pragma unroll
    for (int q = 0; q < 8; ++q) o[q] = (_Float16)va[q];
    *reinterpret_cast<f16x8*>((_Float16*)oa + (size_t)n * D + c0) = o;
  } else {
    f32x4 o0, o1;
#pragma unroll
    for (int q = 0; q < 4; ++q) { o0[q] = va[q]; o1[q] = va[q + 4]; }
    f32x4* op = reinterpret_cast<f32x4*>((float*)oa + (size_t)n * D + c0);
    op[0] = o0; op[1] = o1;
  }

  if (DUAL) {
    f16x8 gb = *reinterpret_cast<const f16x8*>(Gb + (size_t)n * D + c0);
    const f32x4* bpb = reinterpret_cast<const f32x4*>(bb + c0);
    f32x4 bb0 = bpb[0], bb1 = bpb[1];
    float vb[8];
#pragma unroll
    for (int q = 0; q < 8; ++q) {
      float bv = (q < 4) ? bb0[q] : bb1[q - 4];
      vb[q] = accb[q] + (float)gb[q] * di2 + bv;
    }
    f32x4 o0, o1;
#pragma unroll
    for (int q = 0; q < 4; ++q) { o0[q] = vb[q]; o1[q] = vb[q + 4]; }
    f32x4* op = reinterpret_cast<f32x4*>((float*)ob + (size_t)n * D + c0);
    op[0] = o0; op[1] = o1;
  }
}

// ---------------- launcher ----------------
extern "C" void kernel_launch(void* const* d_in, const int* in_sizes, int n_in,
                              void* d_out, int out_size, void* d_ws, size_t ws_size,
                              hipStream_t stream) {
  const int N = in_sizes[0] / D;   // 50000
  const int E = in_sizes[1] / 2;   // 800000

  const float* x        = (const float*)d_in[0];
  const uint32_t* edges = (const uint32_t*)d_in[1];
  const float* W1  = (const float*)d_in[2];
  const float* b1  = (const float*)d_in[3];
  const float* Wmu = (const float*)d_in[4];
  const float* bmu = (const float*)d_in[5];
  const float* Wls = (const float*)d_in[6];
  const float* bls = (const float*)d_in[7];
  float* out_mu = (float*)d_out;
  float* out_ls = out_mu + (size_t)N * D;

  // workspace carve
  char* w = (char*)d_ws;
  uint32_t* deg    = (uint32_t*)(w);                  // N u32
  uint32_t* flag   = (uint32_t*)(w + (256u << 10));   // 1 u32
  uint32_t* bsum   = (uint32_t*)(w + (320u << 10));   // <=64 u32
  uint32_t* rowptr = (uint32_t*)(w + (512u << 10));   // N+1 u32
  uint32_t* cursor = (uint32_t*)(w + (768u << 10));   // N u32
  uint32_t* csr_src= (uint32_t*)(w + (1u << 20));     // E u32 (3.2MB)
  float*    csr_nrm= (float*)(w + (5u << 20));        // E f32 (3.2MB)
  _Float16* G16    = (_Float16*)(w + (9u << 20));     // N*D f16 (conv1 G; reused as Gmu)
  _Float16* h16    = (_Float16*)(w + (22u << 20));    // N*D f16
  _Float16* Gls16  = (_Float16*)(w + (35u << 20));    // N*D f16
  size_t need = (35u << 20) + (size_t)N * D * 2;
  if (ws_size < need) return;

  const int nDeg4 = (N + 3) / 4;
  const int nb = (N + 1023) / 1024;   // 49 for N=50000 (k_scan2 handles any nb)

  k_detect<<<1, 64, 0, stream>>>(edges, flag);
  k_zero4<<<(nDeg4 + 255) / 256, 256, 0, stream>>>((uint4*)deg, nDeg4);
  k_count<<<(E + 255) / 256, 256, 0, stream>>>(edges, flag, deg, E);
  k_scan1<<<nb, 256, 0, stream>>>(deg, bsum, N);
  k_scan2<<<1, 64, 0, stream>>>(bsum, nb);
  k_scan3<<<nb, 256, 0, stream>>>(deg, bsum, rowptr, cursor, N, E);
  k_fill<<<(E + 255) / 256, 256, 0, stream>>>(edges, flag, deg, cursor, csr_src, csr_nrm, E);

  const int gemmGrid = (N + 63) / 64;
  const int aggGrid  = (N * 16 + 255) / 256;

  // conv1: h = relu(agg(x@W1) + b1)
  k_gemm<1><<<gemmGrid, 256, 0, stream>>>((const void*)x, W1, G16, N);
  k_agg<1, 1, 0><<<aggGrid, 256, 0, stream>>>(G16, (const _Float16*)nullptr, rowptr, csr_src,
                                              csr_nrm, deg, b1, (const float*)nullptr,
                                              (void*)h16, (void*)nullptr, N);

  // mu & ls GEMMs fused (Gmu reuses G16 buffer)
  k_gemm2<<<gemmGrid, 256, 0, stream>>>(h16, Wmu, Wls, G16, Gls16, N);

  // fused dual aggregation -> out_mu, out_ls (f32)
  k_agg<0, 0, 1><<<aggGrid, 256, 0, stream>>>(G16, Gls16, rowptr, csr_src, csr_nrm, deg,
                                              bmu, bls, (void*)out_mu, (void*)out_ls, N);
}

// Round 5
// 236.989 us; speedup vs baseline: 35.9962x; 1.1394x over previous
//
#include <hip/hip_runtime.h>
#include <stdint.h>

typedef _Float16 f16x8 __attribute__((ext_vector_type(8)));
typedef float    f32x4 __attribute__((ext_vector_type(4)));

#define D 128

// ---------------- utility ----------------
__global__ void k_zero4(uint4* __restrict__ p, int n4) {
  int t = blockIdx.x * blockDim.x + threadIdx.x;
  if (t < n4) p[t] = make_uint4(0u, 0u, 0u, 0u);
}

// Detect whether edge_index is int64 (odd u32 words all zero) or int32.
__global__ void k_detect(const uint32_t* __restrict__ e, uint32_t* __restrict__ flag) {
  __shared__ uint32_t red[64];
  uint32_t v = 0;
  for (int i = threadIdx.x; i < 1024; i += 64) v |= e[2 * i + 1];
  red[threadIdx.x] = v;
  __syncthreads();
  if (threadIdx.x == 0) {
    uint32_t a = 0;
#pragma unroll
    for (int i = 0; i < 64; ++i) a |= red[i];
    flag[0] = (a == 0u) ? 1u : 0u;
  }
}

__global__ void k_count(const uint32_t* __restrict__ edges, const uint32_t* __restrict__ flag,
                        uint32_t* __restrict__ deg, int E) {
  int e = blockIdx.x * blockDim.x + threadIdx.x;
  if (e >= E) return;
  uint32_t f = flag[0];
  int d = (int)edges[((size_t)(E + e)) << f];
  atomicAdd(&deg[d], 1u);
}

// ---------------- multi-block exclusive scan of deg -> rowptr/cursor ----------------
__global__ __launch_bounds__(256) void k_scan1(const uint32_t* __restrict__ deg,
                                               uint32_t* __restrict__ bsum, int N) {
  int i0 = blockIdx.x * 1024 + threadIdx.x * 4;
  uint32_t s = 0;
  if (i0 + 3 < N) {
    uint4 v = *reinterpret_cast<const uint4*>(deg + i0);
    s = v.x + v.y + v.z + v.w;
  } else {
    for (int j = 0; j < 4; ++j) if (i0 + j < N) s += deg[i0 + j];
  }
#pragma unroll
  for (int off = 1; off < 64; off <<= 1) s += __shfl_xor(s, off);
  __shared__ uint32_t ws[4];
  if ((threadIdx.x & 63) == 0) ws[threadIdx.x >> 6] = s;
  __syncthreads();
  if (threadIdx.x == 0) bsum[blockIdx.x] = ws[0] + ws[1] + ws[2] + ws[3];
}

__global__ void k_scan2(uint32_t* __restrict__ bsum, int nb) {
  int t = threadIdx.x;  // 64 threads
  uint32_t carry = 0;
  for (int base = 0; base < nb; base += 64) {
    uint32_t v = (base + t < nb) ? bsum[base + t] : 0u;
    uint32_t inc = v;
#pragma unroll
    for (int off = 1; off < 64; off <<= 1) {
      uint32_t u = __shfl_up(inc, off);
      if (t >= off) inc += u;
    }
    uint32_t ex = __shfl_up(inc, 1);
    if (t == 0) ex = 0u;
    if (base + t < nb) bsum[base + t] = carry + ex;
    carry += __shfl(inc, 63);
  }
}

__global__ __launch_bounds__(256) void k_scan3(const uint32_t* __restrict__ deg,
                                               const uint32_t* __restrict__ bsum,
                                               uint32_t* __restrict__ rowptr,
                                               uint32_t* __restrict__ cursor, int N, int E) {
  int i0 = blockIdx.x * 1024 + threadIdx.x * 4;
  uint32_t v[4];
  uint32_t s = 0;
#pragma unroll
  for (int j = 0; j < 4; ++j) { v[j] = (i0 + j < N) ? deg[i0 + j] : 0u; s += v[j]; }
  int lane = threadIdx.x & 63, wid = threadIdx.x >> 6;
  uint32_t inc = s;
#pragma unroll
  for (int off = 1; off < 64; off <<= 1) {
    uint32_t u = __shfl_up(inc, off);
    if (lane >= off) inc += u;
  }
  __shared__ uint32_t wsum[4];
  if (lane == 63) wsum[wid] = inc;
  __syncthreads();
  uint32_t woff = 0;
#pragma unroll
  for (int k = 0; k < 4; ++k) if (k < wid) woff += wsum[k];
  uint32_t run = bsum[blockIdx.x] + woff + (inc - s);
#pragma unroll
  for (int j = 0; j < 4; ++j) {
    int i = i0 + j;
    if (i < N) { rowptr[i] = run; cursor[i] = run; }
    run += v[j];
  }
  if (blockIdx.x == 0 && threadIdx.x == 0) rowptr[N] = (uint32_t)E;
}

// Bucket edges by dst: csr_src[pos]=src, csr_nrm[pos]=rsqrt((deg_s+1)(deg_d+1))
__global__ void k_fill(const uint32_t* __restrict__ edges, const uint32_t* __restrict__ flag,
                       const uint32_t* __restrict__ deg, uint32_t* __restrict__ cursor,
                       uint32_t* __restrict__ csr_src, float* __restrict__ csr_nrm, int E) {
  int e = blockIdx.x * blockDim.x + threadIdx.x;
  if (e >= E) return;
  uint32_t f = flag[0];
  int s = (int)edges[(size_t)e << f];
  int d = (int)edges[((size_t)(E + e)) << f];
  uint32_t pos = atomicAdd(&cursor[d], 1u);
  csr_src[pos] = (uint32_t)s;
  csr_nrm[pos] = rsqrtf((float)(deg[s] + 1u) * (float)(deg[d] + 1u));
}

// ---------------- GEMM: out16[N,128] = A[N,128] @ W[128,128] (A f32) ----------------
__global__ __launch_bounds__(256) void k_gemm(const float* __restrict__ A,
                                              const float* __restrict__ W,
                                              _Float16* __restrict__ out, int N)
{
  __shared__ alignas(16) _Float16 xs[64][136];
  __shared__ alignas(16) _Float16 wt[128][136];  // wt[n][k] = W[k][n]

  const int tid  = threadIdx.x;
  const int row0 = blockIdx.x * 64;

  for (int i = tid; i < 64 * 16; i += 256) {
    int r = i >> 4, c = (i & 15) * 8;
    int gr = row0 + r; if (gr >= N) gr = N - 1;
    const f32x4* p = reinterpret_cast<const f32x4*>(A + (size_t)gr * D + c);
    f32x4 a = p[0], b = p[1];
    f16x8 v;
#pragma unroll
    for (int j = 0; j < 4; ++j) { v[j] = (_Float16)a[j]; v[j + 4] = (_Float16)b[j]; }
    *reinterpret_cast<f16x8*>(&xs[r][c]) = v;
  }
  for (int i = tid; i < 128 * 16; i += 256) {
    int k = i >> 4, n0 = (i & 15) * 8;
    const f32x4* p = reinterpret_cast<const f32x4*>(W + k * D + n0);
    f32x4 a = p[0], b = p[1];
#pragma unroll
    for (int j = 0; j < 4; ++j) { wt[n0 + j][k] = (_Float16)a[j]; wt[n0 + 4 + j][k] = (_Float16)b[j]; }
  }
  __syncthreads();

  const int wave = tid >> 6, lane = tid & 63;
  const int m16 = lane & 15, khi = lane >> 4;
  const int wrow = wave * 16;

  f32x4 acc[8] = {};
#pragma unroll
  for (int kk = 0; kk < 4; ++kk) {
    f16x8 a = *reinterpret_cast<const f16x8*>(&xs[wrow + m16][kk * 32 + khi * 8]);
#pragma unroll
    for (int c = 0; c < 8; ++c) {
      f16x8 b = *reinterpret_cast<const f16x8*>(&wt[c * 16 + m16][kk * 32 + khi * 8]);
      acc[c] = __builtin_amdgcn_mfma_f32_16x16x32_f16(a, b, acc[c], 0, 0, 0);
    }
  }

#pragma unroll
  for (int c = 0; c < 8; ++c) {
#pragma unroll
    for (int j = 0; j < 4; ++j) {
      int gr = row0 + wrow + khi * 4 + j;
      if (gr < N) out[(size_t)gr * D + c * 16 + m16] = (_Float16)acc[c][j];
    }
  }
}

// Dual GEMM, f32 out + bias: Oa = A@Wa + ba, Ob = A@Wb + bb  (A f16; stage A once)
__global__ __launch_bounds__(256) void k_gemm2o(const _Float16* __restrict__ A,
                                                const float* __restrict__ Wa,
                                                const float* __restrict__ Wb,
                                                const float* __restrict__ ba,
                                                const float* __restrict__ bb,
                                                float* __restrict__ Oa,
                                                float* __restrict__ Ob, int N)
{
  __shared__ alignas(16) _Float16 xs[64][136];
  __shared__ alignas(16) _Float16 wt[128][136];

  const int tid  = threadIdx.x;
  const int row0 = blockIdx.x * 64;

  for (int i = tid; i < 64 * 16; i += 256) {
    int r = i >> 4, c = (i & 15) * 8;
    int gr = row0 + r; if (gr >= N) gr = N - 1;
    *reinterpret_cast<f16x8*>(&xs[r][c]) =
        *reinterpret_cast<const f16x8*>(A + (size_t)gr * D + c);
  }

  const int wave = tid >> 6, lane = tid & 63;
  const int m16 = lane & 15, khi = lane >> 4;
  const int wrow = wave * 16;

#pragma unroll
  for (int m = 0; m < 2; ++m) {
    const float* W = m ? Wb : Wa;
    const float* bias = m ? bb : ba;
    float* out = m ? Ob : Oa;
    if (m) __syncthreads();  // prior compute's LDS reads done before overwrite
    for (int i = tid; i < 128 * 16; i += 256) {
      int k = i >> 4, n0 = (i & 15) * 8;
      const f32x4* p = reinterpret_cast<const f32x4*>(W + k * D + n0);
      f32x4 a = p[0], b = p[1];
#pragma unroll
      for (int j = 0; j < 4; ++j) { wt[n0 + j][k] = (_Float16)a[j]; wt[n0 + 4 + j][k] = (_Float16)b[j]; }
    }
    __syncthreads();

    f32x4 acc[8] = {};
#pragma unroll
    for (int kk = 0; kk < 4; ++kk) {
      f16x8 a = *reinterpret_cast<const f16x8*>(&xs[wrow + m16][kk * 32 + khi * 8]);
#pragma unroll
      for (int c = 0; c < 8; ++c) {
        f16x8 b = *reinterpret_cast<const f16x8*>(&wt[c * 16 + m16][kk * 32 + khi * 8]);
        acc[c] = __builtin_amdgcn_mfma_f32_16x16x32_f16(a, b, acc[c], 0, 0, 0);
      }
    }
#pragma unroll
    for (int c = 0; c < 8; ++c) {
      float bv = bias[c * 16 + m16];
#pragma unroll
      for (int j = 0; j < 4; ++j) {
        int gr = row0 + wrow + khi * 4 + j;
        if (gr < N) out[(size_t)gr * D + c * 16 + m16] = acc[c][j] + bv;
      }
    }
  }
}

// ---------------- gather-aggregate: out = Â G (+bias, +ReLU optional), f16 out ----------
// out[n] = sum_{e: dst=n} G[src_e]*nrm_e + G[n]/(deg[n]+1) (+ bias)
// 16 threads per node, 8 cols each; 4-deep edge unroll.
template <int RELU, int BIAS>
__global__ __launch_bounds__(256) void k_agg(
    const _Float16* __restrict__ G,
    const uint32_t* __restrict__ rowptr, const uint32_t* __restrict__ csr_src,
    const float* __restrict__ csr_nrm, const uint32_t* __restrict__ deg,
    const float* __restrict__ bias, _Float16* __restrict__ out, int N)
{
  int t = blockIdx.x * blockDim.x + threadIdx.x;
  int n = t >> 4;
  if (n >= N) return;
  int c0 = (t & 15) * 8;

  uint32_t j0 = rowptr[n], j1 = rowptr[n + 1];
  float acc[8] = {};
  uint32_t j = j0;
  for (; j + 4 <= j1; j += 4) {
    uint32_t s0 = csr_src[j], s1 = csr_src[j + 1], s2 = csr_src[j + 2], s3 = csr_src[j + 3];
    float w0 = csr_nrm[j], w1 = csr_nrm[j + 1], w2 = csr_nrm[j + 2], w3 = csr_nrm[j + 3];
    f16x8 h0 = *reinterpret_cast<const f16x8*>(G + (size_t)s0 * D + c0);
    f16x8 h1 = *reinterpret_cast<const f16x8*>(G + (size_t)s1 * D + c0);
    f16x8 h2 = *reinterpret_cast<const f16x8*>(G + (size_t)s2 * D + c0);
    f16x8 h3 = *reinterpret_cast<const f16x8*>(G + (size_t)s3 * D + c0);
#pragma unroll
    for (int q = 0; q < 8; ++q)
      acc[q] += ((float)h0[q] * w0 + (float)h1[q] * w1) + ((float)h2[q] * w2 + (float)h3[q] * w3);
  }
  for (; j < j1; ++j) {
    uint32_t s0 = csr_src[j];
    float w0 = csr_nrm[j];
    f16x8 h0 = *reinterpret_cast<const f16x8*>(G + (size_t)s0 * D + c0);
#pragma unroll
    for (int q = 0; q < 8; ++q) acc[q] += (float)h0[q] * w0;
  }

  float di2 = 1.0f / (float)(deg[n] + 1u);
  f16x8 g = *reinterpret_cast<const f16x8*>(G + (size_t)n * D + c0);
  f32x4 b0 = {}, b1 = {};
  if (BIAS) {
    const f32x4* bp = reinterpret_cast<const f32x4*>(bias + c0);
    b0 = bp[0]; b1 = bp[1];
  }
  f16x8 o;
#pragma unroll
  for (int q = 0; q < 8; ++q) {
    float bv = BIAS ? ((q < 4) ? b0[q] : b1[q - 4]) : 0.0f;
    float r = acc[q] + (float)g[q] * di2 + bv;
    if (RELU) r = r > 0.f ? r : 0.f;
    o[q] = (_Float16)r;
  }
  *reinterpret_cast<f16x8*>(out + (size_t)n * D + c0) = o;
}

// ---------------- launcher ----------------
extern "C" void kernel_launch(void* const* d_in, const int* in_sizes, int n_in,
                              void* d_out, int out_size, void* d_ws, size_t ws_size,
                              hipStream_t stream) {
  const int N = in_sizes[0] / D;   // 50000
  const int E = in_sizes[1] / 2;   // 800000

  const float* x        = (const float*)d_in[0];
  const uint32_t* edges = (const uint32_t*)d_in[1];
  const float* W1  = (const float*)d_in[2];
  const float* b1  = (const float*)d_in[3];
  const float* Wmu = (const float*)d_in[4];
  const float* bmu = (const float*)d_in[5];
  const float* Wls = (const float*)d_in[6];
  const float* bls = (const float*)d_in[7];
  float* out_mu = (float*)d_out;
  float* out_ls = out_mu + (size_t)N * D;

  // workspace carve
  char* w = (char*)d_ws;
  uint32_t* deg    = (uint32_t*)(w);                  // N u32
  uint32_t* flag   = (uint32_t*)(w + (256u << 10));   // 1 u32
  uint32_t* bsum   = (uint32_t*)(w + (320u << 10));   // <=64 u32
  uint32_t* rowptr = (uint32_t*)(w + (512u << 10));   // N+1 u32
  uint32_t* cursor = (uint32_t*)(w + (768u << 10));   // N u32
  uint32_t* csr_src= (uint32_t*)(w + (1u << 20));     // E u32 (3.2MB)
  float*    csr_nrm= (float*)(w + (5u << 20));        // E f32 (3.2MB)
  _Float16* G16    = (_Float16*)(w + (9u << 20));     // N*D f16 (conv1 GEMM out; reused as hagg)
  _Float16* h16    = (_Float16*)(w + (22u << 20));    // N*D f16
  size_t need = (22u << 20) + (size_t)N * D * 2;
  if (ws_size < need) return;

  const int nDeg4 = (N + 3) / 4;
  const int nb = (N + 1023) / 1024;   // 49 for N=50000

  k_detect<<<1, 64, 0, stream>>>(edges, flag);
  k_zero4<<<(nDeg4 + 255) / 256, 256, 0, stream>>>((uint4*)deg, nDeg4);
  k_count<<<(E + 255) / 256, 256, 0, stream>>>(edges, flag, deg, E);
  k_scan1<<<nb, 256, 0, stream>>>(deg, bsum, N);
  k_scan2<<<1, 64, 0, stream>>>(bsum, nb);
  k_scan3<<<nb, 256, 0, stream>>>(deg, bsum, rowptr, cursor, N, E);
  k_fill<<<(E + 255) / 256, 256, 0, stream>>>(edges, flag, deg, cursor, csr_src, csr_nrm, E);

  const int gemmGrid = (N + 63) / 64;
  const int aggGrid  = (N * 16 + 255) / 256;

  // conv1: h = relu(Â(x@W1) + b1)
  k_gemm<<<gemmGrid, 256, 0, stream>>>(x, W1, G16, N);
  k_agg<1, 1><<<aggGrid, 256, 0, stream>>>(G16, rowptr, csr_src, csr_nrm, deg, b1, h16, N);

  // shared aggregation: hagg = Â h   (linearity: Â(hW) = (Âh)W)
  k_agg<0, 0><<<aggGrid, 256, 0, stream>>>(h16, rowptr, csr_src, csr_nrm, deg,
                                           (const float*)nullptr, G16, N);

  // dual GEMM epilogue: out_mu = hagg@Wmu + bmu, out_ls = hagg@Wls + bls (f32)
  k_gemm2o<<<gemmGrid, 256, 0, stream>>>(G16, Wmu, Wls, bmu, bls, out_mu, out_ls, N);
}